// Round 4
// baseline (858.679 us; speedup 1.0000x reference)
//
#include <hip/hip_runtime.h>
#include <hip/hip_bf16.h>

typedef __bf16 bf16;
typedef __bf16 bf16x8 __attribute__((ext_vector_type(8)));
typedef float floatx4 __attribute__((ext_vector_type(4)));

#define MFMA_BF16(a, b, c) __builtin_amdgcn_mfma_f32_16x16x32_bf16((a), (b), (c), 0, 0, 0)

static constexpr int CH = 256;      // channels
static constexpr int NPIX = 9216;   // 96*96
static constexpr int MTOT = 2 * NPIX; // both batches, n-major rows
static constexpr int NAB = 144;     // 128-row attention q-blocks total (2 batches)

// async global->LDS, 16B per lane; LDS dest = wave-uniform base + lane*16
__device__ __forceinline__ void async16(void* lds, const void* g) {
  __builtin_amdgcn_global_load_lds(
      (const __attribute__((address_space(1))) void*)g,
      (__attribute__((address_space(3))) void*)lds, 16, 0, 0);
}

// ---------------------------------------------------------------------------
// Weight split (fp32 -> bf16 hi/lo) + folded BN scale/bias
// ---------------------------------------------------------------------------
__global__ void prep_weights(const float* __restrict__ W,
                             const float* __restrict__ g, const float* __restrict__ b,
                             const float* __restrict__ m, const float* __restrict__ v,
                             bf16* __restrict__ Wh, bf16* __restrict__ Wl,
                             float* __restrict__ scale, float* __restrict__ bias) {
  int i = blockIdx.x * 256 + threadIdx.x;
  if (i < 6 * CH * CH) {
    float w = W[i];
    bf16 h = (bf16)w;
    Wh[i] = h;
    Wl[i] = (bf16)(w - (float)h);
  }
  if (i < 6 * CH) {
    float s = g[i] * rsqrtf(v[i] + 1e-5f);
    scale[i] = s;
    bias[i] = b[i] - m[i] * s;
  }
}

// ---------------------------------------------------------------------------
// Both inputs: fp32 [B][256][9216] (c-major) -> bf16 hi/lo [B*9216][256]
// bid < 1152 -> x, else fk
// ---------------------------------------------------------------------------
__global__ void split_transpose2(const float* __restrict__ xin, const float* __restrict__ fkin,
                                 bf16* __restrict__ ohx, bf16* __restrict__ olx,
                                 bf16* __restrict__ ohf, bf16* __restrict__ olf) {
  __shared__ float t[64][65];
  int bid = blockIdx.x;
  const float* in; bf16 *oh, *ol;
  if (bid >= 1152) { in = fkin; oh = ohf; ol = olf; bid -= 1152; }
  else             { in = xin;  oh = ohx; ol = olx; }
  int b = bid / 576, rem = bid % 576;
  int ct = rem / 144, nt = rem % 144;
  int c0 = ct * 64, n0 = nt * 64;
  int tid = threadIdx.x;
  int cr = tid >> 4, nc = (tid & 15) * 4;
  for (int rr = 0; rr < 64; rr += 16) {
    int c = cr + rr;
    const float* p = in + ((size_t)(b * CH + c0 + c) * NPIX) + n0 + nc;
    float4 val = *(const float4*)p;
    t[c][nc + 0] = val.x; t[c][nc + 1] = val.y;
    t[c][nc + 2] = val.z; t[c][nc + 3] = val.w;
  }
  __syncthreads();
  int n = tid >> 2, cb = (tid & 3) * 16;
  bf16 hb[16], lb[16];
#pragma unroll
  for (int j = 0; j < 16; j++) {
    float xv = t[cb + j][n];
    bf16 h = (bf16)xv;
    hb[j] = h;
    lb[j] = (bf16)(xv - (float)h);
  }
  size_t idx = (size_t)(b * NPIX + n0 + n) * CH + c0 + cb;
  *(bf16x8*)&oh[idx]     = *(bf16x8*)&hb[0];
  *(bf16x8*)&oh[idx + 8] = *(bf16x8*)&hb[8];
  *(bf16x8*)&ol[idx]     = *(bf16x8*)&lb[0];
  *(bf16x8*)&ol[idx + 8] = *(bf16x8*)&lb[8];
}

// ---------------------------------------------------------------------------
// bf16 [B*9216][256] (n-major) -> bf16 [B][256][9216] (c-major)   (for V)
// ---------------------------------------------------------------------------
__global__ void transpose_bf16(const bf16* __restrict__ in, bf16* __restrict__ out) {
  __shared__ bf16 t[64][72];
  int bid = blockIdx.x;
  int b = bid / 576, rem = bid % 576;
  int ct = rem / 144, nt = rem % 144;
  int c0 = ct * 64, n0 = nt * 64;
  int tid = threadIdx.x;
  int nr = tid >> 4, cc = (tid & 15) * 4;
  for (int rr = 0; rr < 64; rr += 16) {
    int n = nr + rr;
    const bf16* p = in + (size_t)(b * NPIX + n0 + n) * CH + c0 + cc;
#pragma unroll
    for (int j = 0; j < 4; j++) t[cc + j][n] = p[j];
  }
  __syncthreads();
  int c = tid >> 2, nb = (tid & 3) * 16;
  bf16 buf[16];
#pragma unroll
  for (int j = 0; j < 16; j++) buf[j] = t[c][nb + j];
  size_t idx = (size_t)(b * CH + c0 + c) * NPIX + n0 + nb;
  *(bf16x8*)&out[idx]     = *(bf16x8*)&buf[0];
  *(bf16x8*)&out[idx + 8] = *(bf16x8*)&buf[8];
}

// ---------------------------------------------------------------------------
// fp32 [B*9216][256] (n-major) -> fp32 [B][256][9216]   (final output)
// ---------------------------------------------------------------------------
__global__ void transpose_out(const float* __restrict__ in, float* __restrict__ out) {
  __shared__ float t[64][65];
  int bid = blockIdx.x;
  int b = bid / 576, rem = bid % 576;
  int ct = rem / 144, nt = rem % 144;
  int c0 = ct * 64, n0 = nt * 64;
  int tid = threadIdx.x;
  int nr = tid >> 4, cc = (tid & 15) * 4;
  for (int rr = 0; rr < 64; rr += 16) {
    int n = nr + rr;
    float4 v = *(const float4*)&in[(size_t)(b * NPIX + n0 + n) * CH + c0 + cc];
    t[cc + 0][n] = v.x; t[cc + 1][n] = v.y; t[cc + 2][n] = v.z; t[cc + 3][n] = v.w;
  }
  __syncthreads();
  int c = tid >> 2, nb = (tid & 3) * 16;
#pragma unroll
  for (int k = 0; k < 4; k++) {
    float4 o4 = make_float4(t[c][nb + 4 * k + 0], t[c][nb + 4 * k + 1],
                            t[c][nb + 4 * k + 2], t[c][nb + 4 * k + 3]);
    *(float4*)&out[(size_t)(b * CH + c0 + c) * NPIX + n0 + nb + 4 * k] = o4;
  }
}

// ---------------------------------------------------------------------------
// Batched split-bf16 conv-GEMM, 128x128 tiles (288 blocks per job).
// mode: 0 = write hi+lo bf16, 1 = hi only, 2 = fp32
// ---------------------------------------------------------------------------
struct ConvJob {
  const bf16 *Ah, *Al, *Bh, *Bl;
  const float *scale, *bias;
  bf16 *Yh, *Yl; float *Yf;
  int mode;
};

__global__ __launch_bounds__(256, 3) void conv128(ConvJob j0, ConvJob j1, ConvJob j2) {
  __shared__ bf16 lds[4][8 * 512];  // planes: Ah, Al, Bh, Bl
  int jid = blockIdx.x / 288;
  int bid = blockIdx.x % 288;
  ConvJob j = (jid == 0) ? j0 : (jid == 1) ? j1 : j2;

  int tid = threadIdx.x;
  int w = tid >> 6, l = tid & 63;
  int q = l >> 4, c16 = l & 15;
  int m0 = (bid >> 1) * 128;
  int o0 = (bid & 1) * 128;

  const bf16* src = (w == 0) ? j.Ah : (w == 1) ? j.Al : (w == 2) ? j.Bh : j.Bl;
  int rowbase = (w < 2) ? m0 : o0;
  const bf16* gp = src + (size_t)(rowbase + c16) * CH + q * 8;
  bf16* ldst = &lds[w][0];

  const floatx4 zero4 = {0.f, 0.f, 0.f, 0.f};
  floatx4 acc[4][4];
#pragma unroll
  for (int i = 0; i < 4; i++)
#pragma unroll
    for (int jj = 0; jj < 4; jj++) acc[i][jj] = zero4;

  int mo16 = (w & 1) * 4, no16 = (w >> 1) * 4;

  for (int k0 = 0; k0 < CH; k0 += 32) {
#pragma unroll
    for (int f = 0; f < 8; f++)
      async16(ldst + f * 512, gp + (size_t)f * 16 * CH + k0);
    __syncthreads();

    bf16x8 ah[4], al[4], bh[4], bl[4];
#pragma unroll
    for (int i = 0; i < 4; i++) {
      ah[i] = *(const bf16x8*)&lds[0][(mo16 + i) * 512 + l * 8];
      al[i] = *(const bf16x8*)&lds[1][(mo16 + i) * 512 + l * 8];
      bh[i] = *(const bf16x8*)&lds[2][(no16 + i) * 512 + l * 8];
      bl[i] = *(const bf16x8*)&lds[3][(no16 + i) * 512 + l * 8];
    }
#pragma unroll
    for (int i = 0; i < 4; i++)
#pragma unroll
      for (int jj = 0; jj < 4; jj++) {
        acc[i][jj] = MFMA_BF16(ah[i], bh[jj], acc[i][jj]);
        acc[i][jj] = MFMA_BF16(ah[i], bl[jj], acc[i][jj]);
        acc[i][jj] = MFMA_BF16(al[i], bh[jj], acc[i][jj]);
      }
    __syncthreads();
  }

  int mo = (w & 1) * 64, no = (w >> 1) * 64;
  float sc[4], bs[4];
#pragma unroll
  for (int jj = 0; jj < 4; jj++) {
    int o = o0 + no + 16 * jj + c16;
    sc[jj] = j.scale[o];
    bs[jj] = j.bias[o];
  }
#pragma unroll
  for (int i = 0; i < 4; i++) {
    int nrow = m0 + mo + 16 * i + 4 * q;
#pragma unroll
    for (int jj = 0; jj < 4; jj++) {
      int o = o0 + no + 16 * jj + c16;
#pragma unroll
      for (int r = 0; r < 4; r++) {
        float y = acc[i][jj][r] * sc[jj] + bs[jj];
        y = fmaxf(y, 0.f);
        size_t idx = (size_t)(nrow + r) * CH + o;
        if (j.mode == 2) {
          j.Yf[idx] = y;
        } else if (j.mode == 1) {
          j.Yh[idx] = (bf16)y;
        } else {
          bf16 h = (bf16)y;
          j.Yh[idx] = h;
          j.Yl[idx] = (bf16)(y - (float)h);
        }
      }
    }
  }
}

// ---------------------------------------------------------------------------
// 64x128-tile split-bf16 conv-GEMM, fp32 out (f_up). Grid 576, LDS 24 KB.
// ---------------------------------------------------------------------------
__global__ __launch_bounds__(256, 4) void conv64(
    const bf16* __restrict__ Ah, const bf16* __restrict__ Al,
    const bf16* __restrict__ Bh, const bf16* __restrict__ Bl,
    const float* __restrict__ scale, const float* __restrict__ bias,
    float* __restrict__ Yf) {
  __shared__ bf16 lds[24 * 512];  // flat frags: [Ah0-3, Al0-3, Bh0-7, Bl0-7]
  int tid = threadIdx.x;
  int w = tid >> 6, l = tid & 63;
  int q = l >> 4, c16 = l & 15;
  int m0 = (blockIdx.x >> 1) * 64;
  int o0 = (blockIdx.x & 1) * 128;

  const floatx4 zero4 = {0.f, 0.f, 0.f, 0.f};
  floatx4 acc[4][2];
#pragma unroll
  for (int i = 0; i < 4; i++) { acc[i][0] = zero4; acc[i][1] = zero4; }

  for (int k0 = 0; k0 < CH; k0 += 32) {
#pragma unroll
    for (int ff = 0; ff < 6; ff++) {
      int f = w * 6 + ff;
      const bf16* src; int rbase, fl;
      if (f < 4)       { src = Ah; rbase = m0; fl = f; }
      else if (f < 8)  { src = Al; rbase = m0; fl = f - 4; }
      else if (f < 16) { src = Bh; rbase = o0; fl = f - 8; }
      else             { src = Bl; rbase = o0; fl = f - 16; }
      async16(&lds[f * 512], src + (size_t)(rbase + fl * 16 + c16) * CH + k0 + q * 8);
    }
    __syncthreads();

    bf16x8 ah[4], al[4], bh[2], bl[2];
#pragma unroll
    for (int i = 0; i < 4; i++) {
      ah[i] = *(const bf16x8*)&lds[(0 + i) * 512 + l * 8];
      al[i] = *(const bf16x8*)&lds[(4 + i) * 512 + l * 8];
    }
#pragma unroll
    for (int n = 0; n < 2; n++) {
      bh[n] = *(const bf16x8*)&lds[(8 + 2 * w + n) * 512 + l * 8];
      bl[n] = *(const bf16x8*)&lds[(16 + 2 * w + n) * 512 + l * 8];
    }
#pragma unroll
    for (int i = 0; i < 4; i++)
#pragma unroll
      for (int n = 0; n < 2; n++) {
        acc[i][n] = MFMA_BF16(ah[i], bh[n], acc[i][n]);
        acc[i][n] = MFMA_BF16(ah[i], bl[n], acc[i][n]);
        acc[i][n] = MFMA_BF16(al[i], bh[n], acc[i][n]);
      }
    __syncthreads();
  }

  float sc[2], bs[2];
#pragma unroll
  for (int n = 0; n < 2; n++) {
    int o = o0 + 32 * w + 16 * n + c16;
    sc[n] = scale[o];
    bs[n] = bias[o];
  }
#pragma unroll
  for (int i = 0; i < 4; i++) {
    int nrow = m0 + 16 * i + 4 * q;
#pragma unroll
    for (int n = 0; n < 2; n++) {
      int o = o0 + 32 * w + 16 * n + c16;
#pragma unroll
      for (int r = 0; r < 4; r++) {
        float y = acc[i][n][r] * sc[n] + bs[n];
        Yf[(size_t)(nrow + r) * CH + o] = fmaxf(y, 0.f);
      }
    }
  }
}

// ---------------------------------------------------------------------------
// Split-KV flash attention partial. BQ=128, BKV=32, d=256, 8 waves.
// Wave w owns q-rows 16w..16w+15 end-to-end: QK -> softmax -> PV (all 256 ch).
// P is wave-local LDS (same-wave DS ordering -> no barrier between phases).
// K and V double-buffered; ONE __syncthreads per iteration (drains next DMA,
// retires reads of current buffers). LDS 72 KB -> 2 blocks/CU = 16 waves.
// ---------------------------------------------------------------------------
__global__ __launch_bounds__(512, 4) void attn_part(
    const bf16* __restrict__ Q, const bf16* __restrict__ K, const bf16* __restrict__ Vt,
    float* __restrict__ Opart, float* __restrict__ Mpart, float* __restrict__ Lpart,
    int niter) {
  __shared__ bf16 lK[2][16 * 512];  // 32 keys x 256 d, frag f = mt*8+kc
  __shared__ bf16 lV[2][16 * 512];  // 256 ch x 32 keys, frag ct = ch/16 (B-layout)
  __shared__ bf16 lP[8 * 512];      // per-wave 1KB: 16 rows x 32 keys, A-frag layout

  int tid = threadIdx.x;
  int w = tid >> 6, l = tid & 63;
  int q = l >> 4, c16 = l & 15;
  int bid = blockIdx.x;
  int qb = bid % NAB, s = bid / NAB;
  int b = qb / 72;
  int n0 = (qb % 72) * 128;
  int kv0 = s * niter * 32;
  size_t qkbase = (size_t)b * NPIX * CH;
  size_t vbase  = (size_t)b * CH * NPIX;

  // register-resident Q fragments: wave w's rows n0+16w+c16 (32 VGPRs)
  bf16x8 qf[8];
  {
    const bf16* qp = Q + qkbase + (size_t)(n0 + 16 * w + c16) * CH + q * 8;
#pragma unroll
    for (int kc = 0; kc < 8; kc++) qf[kc] = *(const bf16x8*)(qp + kc * 32);
  }

  const floatx4 zero4 = {0.f, 0.f, 0.f, 0.f};
  floatx4 oacc[16];  // rows 16w.. (C-layout), ch 16ct+c16 (64 VGPRs)
#pragma unroll
  for (int ct = 0; ct < 16; ct++) oacc[ct] = zero4;
  float mrow[4] = {-1e30f, -1e30f, -1e30f, -1e30f};
  float lrow[4] = {0.f, 0.f, 0.f, 0.f};

  // staging: waves 0-3 stage K (4 frags each), waves 4-7 stage V (4 frags each)
  bool kwave = (w < 4);
  const bf16* gp = kwave ? (K + qkbase + (size_t)kv0 * CH) : (Vt + vbase + kv0);
  size_t lbK = (size_t)c16 * CH + q * 8;    // per-lane offset within K tile row
  size_t lbV = (size_t)c16 * NPIX + q * 8;  // per-lane offset within V tile row

  auto stage = [&](int bi, const bf16* base) {
    if (kwave) {
#pragma unroll
      for (int ff = 0; ff < 4; ff++) {
        int f = 4 * w + ff, mt = f >> 3, kc = f & 7;
        async16(&lK[bi][f * 512], base + (size_t)(mt * 16) * CH + kc * 32 + lbK);
      }
    } else {
#pragma unroll
      for (int ff = 0; ff < 4; ff++) {
        int ct = (w - 4) * 4 + ff;
        async16(&lV[bi][ct * 512], base + (size_t)(ct * 16) * NPIX + lbV);
      }
    }
  };

  stage(0, gp);  // K(0), V(0); drained at first barrier

  for (int it = 0; it < niter; it++) {
    int cur = it & 1;
    __syncthreads();  // buffers `cur` ready; prev iter's reads retired

    if (it + 1 < niter) {
      gp += kwave ? 32 * CH : 32;
      stage(cur ^ 1, gp);
    }

    // S = Q K^T : wave's 16 rows x 32 keys
    floatx4 sf[2] = {zero4, zero4};
#pragma unroll
    for (int mt = 0; mt < 2; mt++)
#pragma unroll
      for (int kc = 0; kc < 8; kc++) {
        bf16x8 kf = *(const bf16x8*)&lK[cur][(mt * 8 + kc) * 512 + l * 8];
        sf[mt] = MFMA_BF16(qf[kc], kf, sf[mt]);
      }

    // online softmax, rows 4q+r (C-layout), reduce over 16 key-lanes
    float alpha[4], rs[4];
#pragma unroll
    for (int r = 0; r < 4; r++) {
      float v2 = fmaxf(sf[0][r], sf[1][r]);
#pragma unroll
      for (int off = 1; off < 16; off <<= 1)
        v2 = fmaxf(v2, __shfl_xor(v2, off));
      float mn = fmaxf(mrow[r], v2);
      alpha[r] = __expf(mrow[r] - mn);
      mrow[r] = mn;
      rs[r] = 0.f;
    }
    // P = exp(S-m) -> wave-local lP in A-frag layout (no barrier needed)
#pragma unroll
    for (int mt = 0; mt < 2; mt++) {
      int base = w * 512 + (2 * mt + (c16 >> 3)) * 128 + (c16 & 7);
#pragma unroll
      for (int r = 0; r < 4; r++) {
        float pv = __expf(sf[mt][r] - mrow[r]);
        rs[r] += pv;
        lP[base + (4 * q + r) * 8] = (bf16)pv;
      }
    }
#pragma unroll
    for (int r = 0; r < 4; r++) {
      float sum = rs[r];
#pragma unroll
      for (int off = 1; off < 16; off <<= 1) sum += __shfl_xor(sum, off);
      lrow[r] = lrow[r] * alpha[r] + sum;
    }

    // rescale O accumulator (alpha lane-mapping == oacc C-layout rows)
    bool upd = (alpha[0] < 1.f) | (alpha[1] < 1.f) | (alpha[2] < 1.f) | (alpha[3] < 1.f);
    if (__ballot((int)upd) != 0ull) {
#pragma unroll
      for (int ct = 0; ct < 16; ct++)
#pragma unroll
        for (int r = 0; r < 4; r++) oacc[ct][r] *= alpha[r];
    }

    // PV: wave's 16 rows x all 256 ch; pa from own lP slab (in-order DS)
    bf16x8 pa = *(const bf16x8*)&lP[w * 512 + l * 8];
#pragma unroll
    for (int ct = 0; ct < 16; ct++) {
      bf16x8 vb = *(const bf16x8*)&lV[cur][ct * 512 + l * 8];
      oacc[ct] = MFMA_BF16(pa, vb, oacc[ct]);
    }
  }

  // write partials (unnormalized O + m, l)
  if (c16 == 0) {
#pragma unroll
    for (int r = 0; r < 4; r++) {
      int row = 16 * w + 4 * q + r;
      Mpart[(size_t)bid * 128 + row] = mrow[r];
      Lpart[(size_t)bid * 128 + row] = lrow[r];
    }
  }
  float* Ob = Opart + (size_t)bid * 128 * CH;
#pragma unroll
  for (int ct = 0; ct < 16; ct++)
#pragma unroll
    for (int r = 0; r < 4; r++) {
      int row = 16 * w + 4 * q + r;
      Ob[(size_t)row * CH + 16 * ct + c16] = oacc[ct][r];
    }
}

// ---------------------------------------------------------------------------
// Combine S partials -> normalized O, split hi/lo bf16, n-major [MTOT][256]
// ---------------------------------------------------------------------------
__global__ __launch_bounds__(256) void attn_combine(
    const float* __restrict__ Opart, const float* __restrict__ Mpart,
    const float* __restrict__ Lpart,
    bf16* __restrict__ Oh, bf16* __restrict__ Ol, int S) {
  __shared__ float wgt[8][128];
  __shared__ float invl[128];
  int qb = blockIdx.x;  // 0..143
  int t = threadIdx.x;
  if (t < 128) {
    float m = -1e30f;
    for (int s = 0; s < S; s++)
      m = fmaxf(m, Mpart[(size_t)(s * NAB + qb) * 128 + t]);
    float lsum = 0.f;
    for (int s = 0; s < S; s++) {
      float wv = __expf(Mpart[(size_t)(s * NAB + qb) * 128 + t] - m);
      wgt[s][t] = wv;
      lsum += wv * Lpart[(size_t)(s * NAB + qb) * 128 + t];
    }
    invl[t] = 1.0f / lsum;
  }
  __syncthreads();
  int c = t;  // 256 threads = 256 channels
  for (int row = 0; row < 128; row++) {
    float acc = 0.f;
    for (int s = 0; s < S; s++)
      acc += wgt[s][row] * Opart[((size_t)(s * NAB + qb) * 128 + row) * CH + c];
    float y = acc * invl[row];
    size_t idx = (size_t)(qb * 128 + row) * CH + c;
    bf16 h = (bf16)y;
    Oh[idx] = h;
    Ol[idx] = (bf16)(y - (float)h);
  }
}

// ---------------------------------------------------------------------------
extern "C" void kernel_launch(void* const* d_in, const int* in_sizes, int n_in,
                              void* d_out, int out_size, void* d_ws, size_t ws_size,
                              hipStream_t stream) {
  const float* x  = (const float*)d_in[0];
  const float* fk = (const float*)d_in[1];
  const float* Ws = (const float*)d_in[2];
  const float* g  = (const float*)d_in[3];
  const float* be = (const float*)d_in[4];
  const float* me = (const float*)d_in[5];
  const float* va = (const float*)d_in[6];
  float* out = (float*)d_out;

  char* p = (char*)d_ws;
  bf16* Wh = (bf16*)p; p += (size_t)6 * CH * CH * 2;
  bf16* Wl = (bf16*)p; p += (size_t)6 * CH * CH * 2;
  float* scale = (float*)p; p += (size_t)6 * CH * 4;
  float* bias  = (float*)p; p += (size_t)6 * CH * 4;
  size_t plane = (size_t)MTOT * CH * 2;  // 9,437,184 B per bf16 plane
  bf16* S0h = (bf16*)p; p += plane;
  bf16* S0l = (bf16*)p; p += plane;
  bf16* Qh  = (bf16*)p; p += plane;
  bf16* Kh  = (bf16*)p; p += plane;
  bf16* Vh  = (bf16*)p; p += plane;
  bf16* Vt  = (bf16*)p; p += plane;
  char* region = p;

  // Overlays inside `region` (all dead before attn_part writes Opart there):
  bf16* S2h = (bf16*)(region);              // fk transposed (hi)
  bf16* S2l = (bf16*)(region + plane);      // fk transposed (lo)
  bf16* P1h = (bf16*)(region + 2 * plane);  // psi1 out (hi)
  bf16* P1l = (bf16*)(region + 3 * plane);  // psi1 out (lo)
  bf16* F1h = (bf16*)(region + 4 * plane);  // phi1 out (hi)
  bf16* F1l = (bf16*)(region + 5 * plane);  // phi1 out (lo)

  size_t base_used = (size_t)(region - (char*)d_ws);
  size_t osz = (size_t)NAB * 128 * CH * 4;            // 18.9 MB per split
  size_t per_split = osz + 2 * (size_t)NAB * 128 * 4;
  long avail = (long)ws_size - (long)base_used;
  int S = 1;
  {
    int cand[5] = {8, 6, 4, 3, 2};
    for (int i = 0; i < 5; i++)
      if ((long)cand[i] * (long)per_split <= avail) { S = cand[i]; break; }
  }
  float* Opart = (float*)region;
  float* Mpart = (float*)(region + (size_t)S * osz);
  float* Lpart = Mpart + (size_t)S * NAB * 128;
  float* Y5 = (float*)region;  // f_up fp32 out, overlays Opart (dead after combine)

  (void)in_sizes; (void)n_in; (void)out_size;

  prep_weights<<<1536, 256, 0, stream>>>(Ws, g, be, me, va, Wh, Wl, scale, bias);
  split_transpose2<<<2304, 256, 0, stream>>>(x, fk, S0h, S0l, S2h, S2l);

  auto W = [&](int layer) { return Wh + (size_t)layer * CH * CH; };
  auto Wlo = [&](int layer) { return Wl + (size_t)layer * CH * CH; };

  ConvJob psi1  {S0h, S0l, W(0), Wlo(0), scale + 0 * CH, bias + 0 * CH, P1h, P1l, nullptr, 0};
  ConvJob phi1  {S2h, S2l, W(2), Wlo(2), scale + 2 * CH, bias + 2 * CH, F1h, F1l, nullptr, 0};
  ConvJob fdown {S2h, S2l, W(4), Wlo(4), scale + 4 * CH, bias + 4 * CH, Vh, nullptr, nullptr, 1};
  ConvJob psi2  {P1h, P1l, W(1), Wlo(1), scale + 1 * CH, bias + 1 * CH, Qh, nullptr, nullptr, 1};
  ConvJob phi2  {F1h, F1l, W(3), Wlo(3), scale + 3 * CH, bias + 3 * CH, Kh, nullptr, nullptr, 1};

  conv128<<<864, 256, 0, stream>>>(psi1, phi1, fdown);
  conv128<<<576, 256, 0, stream>>>(psi2, phi2, phi2);
  transpose_bf16<<<1152, 256, 0, stream>>>(Vh, Vt);
  attn_part<<<NAB * S, 512, 0, stream>>>(Qh, Kh, Vt, Opart, Mpart, Lpart, 288 / S);
  attn_combine<<<NAB, 256, 0, stream>>>(Opart, Mpart, Lpart, S0h, S0l, S);
  conv64<<<576, 256, 0, stream>>>(S0h, S0l, W(5), Wlo(5), scale + 5 * CH, bias + 5 * CH, Y5);
  transpose_out<<<1152, 256, 0, stream>>>(Y5, out);
}

// Round 5
// 670.698 us; speedup vs baseline: 1.2803x; 1.2803x over previous
//
#include <hip/hip_runtime.h>
#include <hip/hip_bf16.h>

typedef __bf16 bf16;
typedef __bf16 bf16x8 __attribute__((ext_vector_type(8)));
typedef float floatx4 __attribute__((ext_vector_type(4)));

#define MFMA_BF16(a, b, c) __builtin_amdgcn_mfma_f32_16x16x32_bf16((a), (b), (c), 0, 0, 0)

static constexpr int CH = 256;      // channels
static constexpr int NPIX = 9216;   // 96*96
static constexpr int MTOT = 2 * NPIX; // both batches, n-major rows
static constexpr int NAB = 144;     // 128-row attention q-blocks total (2 batches)

// async global->LDS, 16B per lane; LDS dest = wave-uniform base + lane*16
__device__ __forceinline__ void async16(void* lds, const void* g) {
  __builtin_amdgcn_global_load_lds(
      (const __attribute__((address_space(1))) void*)g,
      (__attribute__((address_space(3))) void*)lds, 16, 0, 0);
}

// ---------------------------------------------------------------------------
// Weight split (fp32 -> bf16 hi/lo) + folded BN scale/bias
// ---------------------------------------------------------------------------
__global__ void prep_weights(const float* __restrict__ W,
                             const float* __restrict__ g, const float* __restrict__ b,
                             const float* __restrict__ m, const float* __restrict__ v,
                             bf16* __restrict__ Wh, bf16* __restrict__ Wl,
                             float* __restrict__ scale, float* __restrict__ bias) {
  int i = blockIdx.x * 256 + threadIdx.x;
  if (i < 6 * CH * CH) {
    float w = W[i];
    bf16 h = (bf16)w;
    Wh[i] = h;
    Wl[i] = (bf16)(w - (float)h);
  }
  if (i < 6 * CH) {
    float s = g[i] * rsqrtf(v[i] + 1e-5f);
    scale[i] = s;
    bias[i] = b[i] - m[i] * s;
  }
}

// ---------------------------------------------------------------------------
// Both inputs: fp32 [B][256][9216] (c-major) -> bf16 hi/lo [B*9216][256]
// bid < 1152 -> x, else fk
// ---------------------------------------------------------------------------
__global__ void split_transpose2(const float* __restrict__ xin, const float* __restrict__ fkin,
                                 bf16* __restrict__ ohx, bf16* __restrict__ olx,
                                 bf16* __restrict__ ohf, bf16* __restrict__ olf) {
  __shared__ float t[64][65];
  int bid = blockIdx.x;
  const float* in; bf16 *oh, *ol;
  if (bid >= 1152) { in = fkin; oh = ohf; ol = olf; bid -= 1152; }
  else             { in = xin;  oh = ohx; ol = olx; }
  int b = bid / 576, rem = bid % 576;
  int ct = rem / 144, nt = rem % 144;
  int c0 = ct * 64, n0 = nt * 64;
  int tid = threadIdx.x;
  int cr = tid >> 4, nc = (tid & 15) * 4;
  for (int rr = 0; rr < 64; rr += 16) {
    int c = cr + rr;
    const float* p = in + ((size_t)(b * CH + c0 + c) * NPIX) + n0 + nc;
    float4 val = *(const float4*)p;
    t[c][nc + 0] = val.x; t[c][nc + 1] = val.y;
    t[c][nc + 2] = val.z; t[c][nc + 3] = val.w;
  }
  __syncthreads();
  int n = tid >> 2, cb = (tid & 3) * 16;
  bf16 hb[16], lb[16];
#pragma unroll
  for (int j = 0; j < 16; j++) {
    float xv = t[cb + j][n];
    bf16 h = (bf16)xv;
    hb[j] = h;
    lb[j] = (bf16)(xv - (float)h);
  }
  size_t idx = (size_t)(b * NPIX + n0 + n) * CH + c0 + cb;
  *(bf16x8*)&oh[idx]     = *(bf16x8*)&hb[0];
  *(bf16x8*)&oh[idx + 8] = *(bf16x8*)&hb[8];
  *(bf16x8*)&ol[idx]     = *(bf16x8*)&lb[0];
  *(bf16x8*)&ol[idx + 8] = *(bf16x8*)&lb[8];
}

// ---------------------------------------------------------------------------
// bf16 [B*9216][256] (n-major) -> bf16 [B][256][9216] (c-major)   (for V)
// ---------------------------------------------------------------------------
__global__ void transpose_bf16(const bf16* __restrict__ in, bf16* __restrict__ out) {
  __shared__ bf16 t[64][72];
  int bid = blockIdx.x;
  int b = bid / 576, rem = bid % 576;
  int ct = rem / 144, nt = rem % 144;
  int c0 = ct * 64, n0 = nt * 64;
  int tid = threadIdx.x;
  int nr = tid >> 4, cc = (tid & 15) * 4;
  for (int rr = 0; rr < 64; rr += 16) {
    int n = nr + rr;
    const bf16* p = in + (size_t)(b * NPIX + n0 + n) * CH + c0 + cc;
#pragma unroll
    for (int j = 0; j < 4; j++) t[cc + j][n] = p[j];
  }
  __syncthreads();
  int c = tid >> 2, nb = (tid & 3) * 16;
  bf16 buf[16];
#pragma unroll
  for (int j = 0; j < 16; j++) buf[j] = t[c][nb + j];
  size_t idx = (size_t)(b * CH + c0 + c) * NPIX + n0 + nb;
  *(bf16x8*)&out[idx]     = *(bf16x8*)&buf[0];
  *(bf16x8*)&out[idx + 8] = *(bf16x8*)&buf[8];
}

// ---------------------------------------------------------------------------
// fp32 [B*9216][256] (n-major) -> fp32 [B][256][9216]   (final output)
// ---------------------------------------------------------------------------
__global__ void transpose_out(const float* __restrict__ in, float* __restrict__ out) {
  __shared__ float t[64][65];
  int bid = blockIdx.x;
  int b = bid / 576, rem = bid % 576;
  int ct = rem / 144, nt = rem % 144;
  int c0 = ct * 64, n0 = nt * 64;
  int tid = threadIdx.x;
  int nr = tid >> 4, cc = (tid & 15) * 4;
  for (int rr = 0; rr < 64; rr += 16) {
    int n = nr + rr;
    float4 v = *(const float4*)&in[(size_t)(b * NPIX + n0 + n) * CH + c0 + cc];
    t[cc + 0][n] = v.x; t[cc + 1][n] = v.y; t[cc + 2][n] = v.z; t[cc + 3][n] = v.w;
  }
  __syncthreads();
  int c = tid >> 2, nb = (tid & 3) * 16;
#pragma unroll
  for (int k = 0; k < 4; k++) {
    float4 o4 = make_float4(t[c][nb + 4 * k + 0], t[c][nb + 4 * k + 1],
                            t[c][nb + 4 * k + 2], t[c][nb + 4 * k + 3]);
    *(float4*)&out[(size_t)(b * CH + c0 + c) * NPIX + n0 + nb + 4 * k] = o4;
  }
}

// ---------------------------------------------------------------------------
// Batched split-bf16 conv-GEMM, 128x128 tiles (288 blocks per job).
// mode: 0 = write hi+lo bf16, 1 = hi only, 2 = fp32
// ---------------------------------------------------------------------------
struct ConvJob {
  const bf16 *Ah, *Al, *Bh, *Bl;
  const float *scale, *bias;
  bf16 *Yh, *Yl; float *Yf;
  int mode;
};

__global__ __launch_bounds__(256, 3) void conv128(ConvJob j0, ConvJob j1, ConvJob j2) {
  __shared__ bf16 lds[4][8 * 512];  // planes: Ah, Al, Bh, Bl
  int jid = blockIdx.x / 288;
  int bid = blockIdx.x % 288;
  ConvJob j = (jid == 0) ? j0 : (jid == 1) ? j1 : j2;

  int tid = threadIdx.x;
  int w = tid >> 6, l = tid & 63;
  int q = l >> 4, c16 = l & 15;
  int m0 = (bid >> 1) * 128;
  int o0 = (bid & 1) * 128;

  const bf16* src = (w == 0) ? j.Ah : (w == 1) ? j.Al : (w == 2) ? j.Bh : j.Bl;
  int rowbase = (w < 2) ? m0 : o0;
  const bf16* gp = src + (size_t)(rowbase + c16) * CH + q * 8;
  bf16* ldst = &lds[w][0];

  const floatx4 zero4 = {0.f, 0.f, 0.f, 0.f};
  floatx4 acc[4][4];
#pragma unroll
  for (int i = 0; i < 4; i++)
#pragma unroll
    for (int jj = 0; jj < 4; jj++) acc[i][jj] = zero4;

  int mo16 = (w & 1) * 4, no16 = (w >> 1) * 4;

  for (int k0 = 0; k0 < CH; k0 += 32) {
#pragma unroll
    for (int f = 0; f < 8; f++)
      async16(ldst + f * 512, gp + (size_t)f * 16 * CH + k0);
    __syncthreads();

    bf16x8 ah[4], al[4], bh[4], bl[4];
#pragma unroll
    for (int i = 0; i < 4; i++) {
      ah[i] = *(const bf16x8*)&lds[0][(mo16 + i) * 512 + l * 8];
      al[i] = *(const bf16x8*)&lds[1][(mo16 + i) * 512 + l * 8];
      bh[i] = *(const bf16x8*)&lds[2][(no16 + i) * 512 + l * 8];
      bl[i] = *(const bf16x8*)&lds[3][(no16 + i) * 512 + l * 8];
    }
#pragma unroll
    for (int i = 0; i < 4; i++)
#pragma unroll
      for (int jj = 0; jj < 4; jj++) {
        acc[i][jj] = MFMA_BF16(ah[i], bh[jj], acc[i][jj]);
        acc[i][jj] = MFMA_BF16(ah[i], bl[jj], acc[i][jj]);
        acc[i][jj] = MFMA_BF16(al[i], bh[jj], acc[i][jj]);
      }
    __syncthreads();
  }

  int mo = (w & 1) * 64, no = (w >> 1) * 64;
  float sc[4], bs[4];
#pragma unroll
  for (int jj = 0; jj < 4; jj++) {
    int o = o0 + no + 16 * jj + c16;
    sc[jj] = j.scale[o];
    bs[jj] = j.bias[o];
  }
#pragma unroll
  for (int i = 0; i < 4; i++) {
    int nrow = m0 + mo + 16 * i + 4 * q;
#pragma unroll
    for (int jj = 0; jj < 4; jj++) {
      int o = o0 + no + 16 * jj + c16;
#pragma unroll
      for (int r = 0; r < 4; r++) {
        float y = acc[i][jj][r] * sc[jj] + bs[jj];
        y = fmaxf(y, 0.f);
        size_t idx = (size_t)(nrow + r) * CH + o;
        if (j.mode == 2) {
          j.Yf[idx] = y;
        } else if (j.mode == 1) {
          j.Yh[idx] = (bf16)y;
        } else {
          bf16 h = (bf16)y;
          j.Yh[idx] = h;
          j.Yl[idx] = (bf16)(y - (float)h);
        }
      }
    }
  }
}

// ---------------------------------------------------------------------------
// 64x128-tile split-bf16 conv-GEMM, fp32 out (f_up). Grid 576, LDS 24 KB.
// ---------------------------------------------------------------------------
__global__ __launch_bounds__(256, 4) void conv64(
    const bf16* __restrict__ Ah, const bf16* __restrict__ Al,
    const bf16* __restrict__ Bh, const bf16* __restrict__ Bl,
    const float* __restrict__ scale, const float* __restrict__ bias,
    float* __restrict__ Yf) {
  __shared__ bf16 lds[24 * 512];  // flat frags: [Ah0-3, Al0-3, Bh0-7, Bl0-7]
  int tid = threadIdx.x;
  int w = tid >> 6, l = tid & 63;
  int q = l >> 4, c16 = l & 15;
  int m0 = (blockIdx.x >> 1) * 64;
  int o0 = (blockIdx.x & 1) * 128;

  const floatx4 zero4 = {0.f, 0.f, 0.f, 0.f};
  floatx4 acc[4][2];
#pragma unroll
  for (int i = 0; i < 4; i++) { acc[i][0] = zero4; acc[i][1] = zero4; }

  for (int k0 = 0; k0 < CH; k0 += 32) {
#pragma unroll
    for (int ff = 0; ff < 6; ff++) {
      int f = w * 6 + ff;
      const bf16* src; int rbase, fl;
      if (f < 4)       { src = Ah; rbase = m0; fl = f; }
      else if (f < 8)  { src = Al; rbase = m0; fl = f - 4; }
      else if (f < 16) { src = Bh; rbase = o0; fl = f - 8; }
      else             { src = Bl; rbase = o0; fl = f - 16; }
      async16(&lds[f * 512], src + (size_t)(rbase + fl * 16 + c16) * CH + k0 + q * 8);
    }
    __syncthreads();

    bf16x8 ah[4], al[4], bh[2], bl[2];
#pragma unroll
    for (int i = 0; i < 4; i++) {
      ah[i] = *(const bf16x8*)&lds[(0 + i) * 512 + l * 8];
      al[i] = *(const bf16x8*)&lds[(4 + i) * 512 + l * 8];
    }
#pragma unroll
    for (int n = 0; n < 2; n++) {
      bh[n] = *(const bf16x8*)&lds[(8 + 2 * w + n) * 512 + l * 8];
      bl[n] = *(const bf16x8*)&lds[(16 + 2 * w + n) * 512 + l * 8];
    }
#pragma unroll
    for (int i = 0; i < 4; i++)
#pragma unroll
      for (int n = 0; n < 2; n++) {
        acc[i][n] = MFMA_BF16(ah[i], bh[n], acc[i][n]);
        acc[i][n] = MFMA_BF16(ah[i], bl[n], acc[i][n]);
        acc[i][n] = MFMA_BF16(al[i], bh[n], acc[i][n]);
      }
    __syncthreads();
  }

  float sc[2], bs[2];
#pragma unroll
  for (int n = 0; n < 2; n++) {
    int o = o0 + 32 * w + 16 * n + c16;
    sc[n] = scale[o];
    bs[n] = bias[o];
  }
#pragma unroll
  for (int i = 0; i < 4; i++) {
    int nrow = m0 + 16 * i + 4 * q;
#pragma unroll
    for (int n = 0; n < 2; n++) {
      int o = o0 + 32 * w + 16 * n + c16;
#pragma unroll
      for (int r = 0; r < 4; r++) {
        float y = acc[i][n][r] * sc[n] + bs[n];
        Yf[(size_t)(nrow + r) * CH + o] = fmaxf(y, 0.f);
      }
    }
  }
}

// ---------------------------------------------------------------------------
// Split-KV flash attention partial. BQ=128, BKV=32, d=256, 8 waves.
// Wave w owns q-rows 16w..16w+15 end-to-end: QK -> softmax -> PV (all 256 ch).
// P is wave-local LDS (same-wave DS ordering -> no barrier between phases).
// K and V double-buffered; ONE __syncthreads per iteration.
// __launch_bounds__(512, 2): empirically (R4) the 2nd arg acts as co-resident
// BLOCKS; (512,4) capped VGPR at 64 and spilled ~70 regs/iter (613 MB scratch
// writes). 2 blocks -> 16 waves/CU -> 128-VGPR cap; live state ~104+transients.
// ---------------------------------------------------------------------------
__global__ __launch_bounds__(512, 2) void attn_part(
    const bf16* __restrict__ Q, const bf16* __restrict__ K, const bf16* __restrict__ Vt,
    float* __restrict__ Opart, float* __restrict__ Mpart, float* __restrict__ Lpart,
    int niter) {
  __shared__ bf16 lK[2][16 * 512];  // 32 keys x 256 d, frag f = mt*8+kc
  __shared__ bf16 lV[2][16 * 512];  // 256 ch x 32 keys, frag ct = ch/16 (B-layout)
  __shared__ bf16 lP[8 * 512];      // per-wave 1KB: 16 rows x 32 keys, A-frag layout

  int tid = threadIdx.x;
  int w = tid >> 6, l = tid & 63;
  int q = l >> 4, c16 = l & 15;
  int bid = blockIdx.x;
  int qb = bid % NAB, s = bid / NAB;
  int b = qb / 72;
  int n0 = (qb % 72) * 128;
  int kv0 = s * niter * 32;
  size_t qkbase = (size_t)b * NPIX * CH;
  size_t vbase  = (size_t)b * CH * NPIX;

  // register-resident Q fragments: wave w's rows n0+16w+c16 (32 VGPRs)
  bf16x8 qf[8];
  {
    const bf16* qp = Q + qkbase + (size_t)(n0 + 16 * w + c16) * CH + q * 8;
#pragma unroll
    for (int kc = 0; kc < 8; kc++) qf[kc] = *(const bf16x8*)(qp + kc * 32);
  }

  const floatx4 zero4 = {0.f, 0.f, 0.f, 0.f};
  floatx4 oacc[16];  // rows 16w.. (C-layout), ch 16ct+c16 (64 VGPRs)
#pragma unroll
  for (int ct = 0; ct < 16; ct++) oacc[ct] = zero4;
  float mrow[4] = {-1e30f, -1e30f, -1e30f, -1e30f};
  float lrow[4] = {0.f, 0.f, 0.f, 0.f};

  // staging: waves 0-3 stage K (4 frags each), waves 4-7 stage V (4 frags each)
  bool kwave = (w < 4);
  const bf16* gp = kwave ? (K + qkbase + (size_t)kv0 * CH) : (Vt + vbase + kv0);
  size_t lbK = (size_t)c16 * CH + q * 8;    // per-lane offset within K tile row
  size_t lbV = (size_t)c16 * NPIX + q * 8;  // per-lane offset within V tile row

  auto stage = [&](int bi, const bf16* base) {
    if (kwave) {
#pragma unroll
      for (int ff = 0; ff < 4; ff++) {
        int f = 4 * w + ff, mt = f >> 3, kc = f & 7;
        async16(&lK[bi][f * 512], base + (size_t)(mt * 16) * CH + kc * 32 + lbK);
      }
    } else {
#pragma unroll
      for (int ff = 0; ff < 4; ff++) {
        int ct = (w - 4) * 4 + ff;
        async16(&lV[bi][ct * 512], base + (size_t)(ct * 16) * NPIX + lbV);
      }
    }
  };

  stage(0, gp);  // K(0), V(0); drained at first barrier

  for (int it = 0; it < niter; it++) {
    int cur = it & 1;
    __syncthreads();  // buffers `cur` ready; prev iter's reads retired

    if (it + 1 < niter) {
      gp += kwave ? 32 * CH : 32;
      stage(cur ^ 1, gp);
    }

    // S = Q K^T : wave's 16 rows x 32 keys
    floatx4 sf[2] = {zero4, zero4};
#pragma unroll
    for (int mt = 0; mt < 2; mt++)
#pragma unroll
      for (int kc = 0; kc < 8; kc++) {
        bf16x8 kf = *(const bf16x8*)&lK[cur][(mt * 8 + kc) * 512 + l * 8];
        sf[mt] = MFMA_BF16(qf[kc], kf, sf[mt]);
      }

    // online softmax, rows 4q+r (C-layout), reduce over 16 key-lanes
    float alpha[4], rs[4];
#pragma unroll
    for (int r = 0; r < 4; r++) {
      float v2 = fmaxf(sf[0][r], sf[1][r]);
#pragma unroll
      for (int off = 1; off < 16; off <<= 1)
        v2 = fmaxf(v2, __shfl_xor(v2, off));
      float mn = fmaxf(mrow[r], v2);
      alpha[r] = __expf(mrow[r] - mn);
      mrow[r] = mn;
      rs[r] = 0.f;
    }
    // P = exp(S-m) -> wave-local lP in A-frag layout (no barrier needed)
#pragma unroll
    for (int mt = 0; mt < 2; mt++) {
      int base = w * 512 + (2 * mt + (c16 >> 3)) * 128 + (c16 & 7);
#pragma unroll
      for (int r = 0; r < 4; r++) {
        float pv = __expf(sf[mt][r] - mrow[r]);
        rs[r] += pv;
        lP[base + (4 * q + r) * 8] = (bf16)pv;
      }
    }
#pragma unroll
    for (int r = 0; r < 4; r++) {
      float sum = rs[r];
#pragma unroll
      for (int off = 1; off < 16; off <<= 1) sum += __shfl_xor(sum, off);
      lrow[r] = lrow[r] * alpha[r] + sum;
    }

    // rescale O accumulator (alpha lane-mapping == oacc C-layout rows)
    bool upd = (alpha[0] < 1.f) | (alpha[1] < 1.f) | (alpha[2] < 1.f) | (alpha[3] < 1.f);
    if (__ballot((int)upd) != 0ull) {
#pragma unroll
      for (int ct = 0; ct < 16; ct++)
#pragma unroll
        for (int r = 0; r < 4; r++) oacc[ct][r] *= alpha[r];
    }

    // PV: wave's 16 rows x all 256 ch; pa from own lP slab (in-order DS)
    bf16x8 pa = *(const bf16x8*)&lP[w * 512 + l * 8];
#pragma unroll
    for (int ct = 0; ct < 16; ct++) {
      bf16x8 vb = *(const bf16x8*)&lV[cur][ct * 512 + l * 8];
      oacc[ct] = MFMA_BF16(pa, vb, oacc[ct]);
    }
  }

  // write partials (unnormalized O + m, l)
  if (c16 == 0) {
#pragma unroll
    for (int r = 0; r < 4; r++) {
      int row = 16 * w + 4 * q + r;
      Mpart[(size_t)bid * 128 + row] = mrow[r];
      Lpart[(size_t)bid * 128 + row] = lrow[r];
    }
  }
  float* Ob = Opart + (size_t)bid * 128 * CH;
#pragma unroll
  for (int ct = 0; ct < 16; ct++)
#pragma unroll
    for (int r = 0; r < 4; r++) {
      int row = 16 * w + 4 * q + r;
      Ob[(size_t)row * CH + 16 * ct + c16] = oacc[ct][r];
    }
}

// ---------------------------------------------------------------------------
// Combine S partials -> normalized O, split hi/lo bf16, n-major [MTOT][256]
// ---------------------------------------------------------------------------
__global__ __launch_bounds__(256) void attn_combine(
    const float* __restrict__ Opart, const float* __restrict__ Mpart,
    const float* __restrict__ Lpart,
    bf16* __restrict__ Oh, bf16* __restrict__ Ol, int S) {
  __shared__ float wgt[8][128];
  __shared__ float invl[128];
  int qb = blockIdx.x;  // 0..143
  int t = threadIdx.x;
  if (t < 128) {
    float m = -1e30f;
    for (int s = 0; s < S; s++)
      m = fmaxf(m, Mpart[(size_t)(s * NAB + qb) * 128 + t]);
    float lsum = 0.f;
    for (int s = 0; s < S; s++) {
      float wv = __expf(Mpart[(size_t)(s * NAB + qb) * 128 + t] - m);
      wgt[s][t] = wv;
      lsum += wv * Lpart[(size_t)(s * NAB + qb) * 128 + t];
    }
    invl[t] = 1.0f / lsum;
  }
  __syncthreads();
  int c = t;  // 256 threads = 256 channels
  for (int row = 0; row < 128; row++) {
    float acc = 0.f;
    for (int s = 0; s < S; s++)
      acc += wgt[s][row] * Opart[((size_t)(s * NAB + qb) * 128 + row) * CH + c];
    float y = acc * invl[row];
    size_t idx = (size_t)(qb * 128 + row) * CH + c;
    bf16 h = (bf16)y;
    Oh[idx] = h;
    Ol[idx] = (bf16)(y - (float)h);
  }
}

// ---------------------------------------------------------------------------
extern "C" void kernel_launch(void* const* d_in, const int* in_sizes, int n_in,
                              void* d_out, int out_size, void* d_ws, size_t ws_size,
                              hipStream_t stream) {
  const float* x  = (const float*)d_in[0];
  const float* fk = (const float*)d_in[1];
  const float* Ws = (const float*)d_in[2];
  const float* g  = (const float*)d_in[3];
  const float* be = (const float*)d_in[4];
  const float* me = (const float*)d_in[5];
  const float* va = (const float*)d_in[6];
  float* out = (float*)d_out;

  char* p = (char*)d_ws;
  bf16* Wh = (bf16*)p; p += (size_t)6 * CH * CH * 2;
  bf16* Wl = (bf16*)p; p += (size_t)6 * CH * CH * 2;
  float* scale = (float*)p; p += (size_t)6 * CH * 4;
  float* bias  = (float*)p; p += (size_t)6 * CH * 4;
  size_t plane = (size_t)MTOT * CH * 2;  // 9,437,184 B per bf16 plane
  bf16* S0h = (bf16*)p; p += plane;
  bf16* S0l = (bf16*)p; p += plane;
  bf16* Qh  = (bf16*)p; p += plane;
  bf16* Kh  = (bf16*)p; p += plane;
  bf16* Vh  = (bf16*)p; p += plane;
  bf16* Vt  = (bf16*)p; p += plane;
  char* region = p;

  // Overlays inside `region` (all dead before attn_part writes Opart there):
  bf16* S2h = (bf16*)(region);              // fk transposed (hi)
  bf16* S2l = (bf16*)(region + plane);      // fk transposed (lo)
  bf16* P1h = (bf16*)(region + 2 * plane);  // psi1 out (hi)
  bf16* P1l = (bf16*)(region + 3 * plane);  // psi1 out (lo)
  bf16* F1h = (bf16*)(region + 4 * plane);  // phi1 out (hi)
  bf16* F1l = (bf16*)(region + 5 * plane);  // phi1 out (lo)

  size_t base_used = (size_t)(region - (char*)d_ws);
  size_t osz = (size_t)NAB * 128 * CH * 4;            // 18.9 MB per split
  size_t per_split = osz + 2 * (size_t)NAB * 128 * 4;
  long avail = (long)ws_size - (long)base_used;
  int S = 1;
  {
    int cand[5] = {8, 6, 4, 3, 2};
    for (int i = 0; i < 5; i++)
      if ((long)cand[i] * (long)per_split <= avail) { S = cand[i]; break; }
  }
  float* Opart = (float*)region;
  float* Mpart = (float*)(region + (size_t)S * osz);
  float* Lpart = Mpart + (size_t)S * NAB * 128;
  float* Y5 = (float*)region;  // f_up fp32 out, overlays Opart (dead after combine)

  (void)in_sizes; (void)n_in; (void)out_size;

  prep_weights<<<1536, 256, 0, stream>>>(Ws, g, be, me, va, Wh, Wl, scale, bias);
  split_transpose2<<<2304, 256, 0, stream>>>(x, fk, S0h, S0l, S2h, S2l);

  auto W = [&](int layer) { return Wh + (size_t)layer * CH * CH; };
  auto Wlo = [&](int layer) { return Wl + (size_t)layer * CH * CH; };

  ConvJob psi1  {S0h, S0l, W(0), Wlo(0), scale + 0 * CH, bias + 0 * CH, P1h, P1l, nullptr, 0};
  ConvJob phi1  {S2h, S2l, W(2), Wlo(2), scale + 2 * CH, bias + 2 * CH, F1h, F1l, nullptr, 0};
  ConvJob fdown {S2h, S2l, W(4), Wlo(4), scale + 4 * CH, bias + 4 * CH, Vh, nullptr, nullptr, 1};
  ConvJob psi2  {P1h, P1l, W(1), Wlo(1), scale + 1 * CH, bias + 1 * CH, Qh, nullptr, nullptr, 1};
  ConvJob phi2  {F1h, F1l, W(3), Wlo(3), scale + 3 * CH, bias + 3 * CH, Kh, nullptr, nullptr, 1};

  conv128<<<864, 256, 0, stream>>>(psi1, phi1, fdown);
  conv128<<<576, 256, 0, stream>>>(psi2, phi2, phi2);
  transpose_bf16<<<1152, 256, 0, stream>>>(Vh, Vt);
  attn_part<<<NAB * S, 512, 0, stream>>>(Qh, Kh, Vt, Opart, Mpart, Lpart, 288 / S);
  attn_combine<<<NAB, 256, 0, stream>>>(Opart, Mpart, Lpart, S0h, S0l, S);
  conv64<<<576, 256, 0, stream>>>(S0h, S0l, W(5), Wlo(5), scale + 5 * CH, bias + 5 * CH, Y5);
  transpose_out<<<1152, 256, 0, stream>>>(Y5, out);
}